// Round 14
// baseline (592.458 us; speedup 1.0000x reference)
//
#include <hip/hip_runtime.h>
#include <hip/hip_bf16.h>
#include <cstdint>
#include <cstddef>

#define B_   128
#define NCH  64
#define T_   30720
#define TW   256          // tile t-width: 1 KB contiguous per channel per tile
#define EPSF 1e-12f
#define THRF 0.5f

typedef float  f32x4 __attribute__((ext_vector_type(4)));
typedef short  s16x8 __attribute__((ext_vector_type(8)));
typedef unsigned short u16;

#define AS1 __attribute__((address_space(1)))
#define AS3 __attribute__((address_space(3)))

static __device__ __forceinline__ short bf16s(float f) {
    return (short)__builtin_bit_cast(u16, __float2bfloat16(f));
}

// ---------------------------------------------------------------------------
// ABLATION ROUND: R13's fused stage1 split into two independently-correct
// kernels to finally measure where the 418 us goes (m177: ablate before
// optimizing). corr_gram = R13 minus the out_x store (writes P,S).
// corr_copy = dedicated barrier-free copy (writes out_x). Sum of outputs
// identical to R13's stage1.
// ---------------------------------------------------------------------------

// ============ GRAM-ONLY: R13 structure, out_x store deleted ============
__global__ __launch_bounds__(1024) void corr_gram(
    const float* __restrict__ x,
    float* __restrict__ P, float* __restrict__ S,
    int split, int Tc)
{
    extern __shared__ __align__(16) float lds[];   // [2][64][TW] = 128 KB

    const int tid  = threadIdx.x;
    const int lane = tid & 63;
    const int w    = tid >> 6;          // wave 0..15

    const int bid = blockIdx.x;
    const int b   = bid / split;
    const int c   = bid - b * split;

    const size_t base = (size_t)b * ((size_t)NCH * T_) + (size_t)c * Tc;
    const float* xw = x + base;

    const int NT  = Tc / TW;            // 60
    const int BUF = NCH * TW;           // 16384

    auto dma = [&](int tile, int buf) {
        #pragma unroll
        for (int i = 0; i < 4; ++i) {
            const int r  = w * 4 + i;
            const int gg = lane ^ (r & 7);            // pre-swizzled source
            const float* src = xw + (size_t)r * T_ + (size_t)(tile * TW + gg * 4);
            float* dst = &lds[buf * BUF + r * TW];
            __builtin_amdgcn_global_load_lds((const AS1 void*)src,
                                             (AS3 void*)dst, 16, 0, 0);
        }
    };

    dma(0, 0);
    asm volatile("s_waitcnt vmcnt(0)" ::: "memory");
    __builtin_amdgcn_s_barrier();
    __builtin_amdgcn_sched_barrier(0);

    if (w < 8) {
        // ==== sum waves: ds_read rows + fp32 sums (NO global store) ====
        float csum[8];
        #pragma unroll
        for (int i = 0; i < 8; ++i) csum[i] = 0.f;

        for (int t = 0; t < NT; ++t) {
            const int cur = t & 1;
            if (t + 1 < NT) dma(t + 1, cur ^ 1);

            #pragma unroll
            for (int i = 0; i < 8; ++i) {
                const int row  = w * 8 + i;
                const int slot = lane ^ (row & 7);
                const f32x4 v = *reinterpret_cast<const f32x4*>(
                    &lds[cur * BUF + row * TW + slot * 4]);
                csum[i] += ((v.x + v.y) + (v.z + v.w));
            }

            asm volatile("s_waitcnt vmcnt(0)" ::: "memory");  // DMA(t+1) done
            __builtin_amdgcn_s_barrier();
            __builtin_amdgcn_sched_barrier(0);
        }

        __syncthreads();

        #pragma unroll
        for (int i = 0; i < 8; ++i) {
            float v = csum[i];
            v += __shfl_xor(v, 1,  64);
            v += __shfl_xor(v, 2,  64);
            v += __shfl_xor(v, 4,  64);
            v += __shfl_xor(v, 8,  64);
            v += __shfl_xor(v, 16, 64);
            v += __shfl_xor(v, 32, 64);
            if (lane == 0)
                S[(size_t)bid * NCH + w * 8 + i] = v;
        }
    } else {
        // ==== GRAM waves: identical to R13 ====
        const int g   = w - 8;
        const int q   = g & 3;
        const int par = g >> 2;
        const int qr  = q >> 1, qc = q & 1;
        const int fr  = lane & 15;
        const int g8  = lane >> 4;
        const int fs  = fr & 7;

        f32x4 acc[2][2];
        #pragma unroll
        for (int rb = 0; rb < 2; ++rb)
            #pragma unroll
            for (int cb = 0; cb < 2; ++cb) acc[rb][cb] = (f32x4)(0.f);

        for (int t = 0; t < NT; ++t) {
            const int cur = t & 1;
            if (t + 1 < NT) dma(t + 1, cur ^ 1);

            #pragma unroll
            for (int kk = 0; kk < 4; ++kk) {
                const int ks = par + 2 * kk;
                const int gl = (ks * 8 + 2 * g8) ^ fs;
                const int gh = (ks * 8 + 2 * g8 + 1) ^ fs;
                s16x8 frag[4];
                #pragma unroll
                for (int e = 0; e < 4; ++e) {
                    const int blk = (e < 2) ? (2 * qr + e) : (2 * qc + (e - 2));
                    const int ro  = cur * BUF + (blk * 16 + fr) * TW;
                    const f32x4 lo = *reinterpret_cast<const f32x4*>(&lds[ro + gl * 4]);
                    const f32x4 hv = *reinterpret_cast<const f32x4*>(&lds[ro + gh * 4]);
                    frag[e][0] = bf16s(lo.x); frag[e][1] = bf16s(lo.y);
                    frag[e][2] = bf16s(lo.z); frag[e][3] = bf16s(lo.w);
                    frag[e][4] = bf16s(hv.x); frag[e][5] = bf16s(hv.y);
                    frag[e][6] = bf16s(hv.z); frag[e][7] = bf16s(hv.w);
                }
                #pragma unroll
                for (int rb = 0; rb < 2; ++rb)
                    #pragma unroll
                    for (int cb = 0; cb < 2; ++cb)
                        acc[rb][cb] = __builtin_amdgcn_mfma_f32_16x16x32_bf16(
                            frag[rb], frag[2 + cb], acc[rb][cb], 0, 0, 0);
            }

            asm volatile("s_waitcnt vmcnt(0)" ::: "memory");
            __builtin_amdgcn_s_barrier();
            __builtin_amdgcn_sched_barrier(0);
        }

        if (par == 1) {
            #pragma unroll
            for (int rb = 0; rb < 2; ++rb)
                #pragma unroll
                for (int cb = 0; cb < 2; ++cb)
                    #pragma unroll
                    for (int reg = 0; reg < 4; ++reg)
                        lds[q * 1024 + lane * 16 + rb * 8 + cb * 4 + reg]
                            = acc[rb][cb][reg];
        }

        __syncthreads();

        if (par == 0) {
            float* Pc = P + ((size_t)bid << 12);
            const int prow = (lane >> 4) << 2;
            const int pcol = lane & 15;
            #pragma unroll
            for (int rb = 0; rb < 2; ++rb)
                #pragma unroll
                for (int cb = 0; cb < 2; ++cb)
                    #pragma unroll
                    for (int reg = 0; reg < 4; ++reg)
                        Pc[((2 * qr + rb) * 16 + prow + reg) * 64
                           + (2 * qc + cb) * 16 + pcol]
                            = acc[rb][cb][reg]
                            + lds[q * 1024 + lane * 16 + rb * 8 + cb * 4 + reg];
        }
    }
}

// ============ COPY-ONLY: barrier-free, per-wave self-paced ============
// Wave w owns rows 4w..4w+3 of its chunk; private LDS [2][4][256] (8 KB).
// Per tile: issue 4 DMA (next tile), counted vmcnt (DMA(t) retired, own
// stores in flight), 4x {ds_read_b128 -> contiguous 1 KB cached store}.
// Zero barriers, zero cross-wave coupling: pure copy machinery measurement.
__global__ __launch_bounds__(1024) void corr_copy(
    const float* __restrict__ x, float* __restrict__ out_x,
    int split, int Tc)
{
    extern __shared__ __align__(16) float ldsc[];  // [16][2][4][256] = 128 KB

    const int tid  = threadIdx.x;
    const int lane = tid & 63;
    const int w    = tid >> 6;          // wave 0..15

    const int bid = blockIdx.x;
    const int b   = bid / split;
    const int c   = bid - b * split;

    const size_t base = (size_t)b * ((size_t)NCH * T_) + (size_t)c * Tc
                      + (size_t)(w * 4) * T_;
    const float* xw = x + base;
    float*       ow = out_x + base;

    const int NT = Tc / TW;             // 60
    float* Lw = &ldsc[w * 2048];        // wave-private

    auto dma = [&](int tile, int buf) {
        #pragma unroll
        for (int i = 0; i < 4; ++i) {
            const float* src = xw + (size_t)i * T_ + (size_t)(tile * TW + lane * 4);
            float* dst = Lw + buf * 1024 + i * 256;   // linear, no swizzle
            __builtin_amdgcn_global_load_lds((const AS1 void*)src,
                                             (AS3 void*)dst, 16, 0, 0);
        }
    };

    dma(0, 0);

    for (int t = 0; t < NT; ++t) {
        const int cur = t & 1;
        if (t + 1 < NT) dma(t + 1, cur ^ 1);

        // queue: [DMA(t)4, ST(t-1)4, DMA(t+1)4]; wait DMA(t) retired.
        if (t == 0 || t + 1 == NT) {
            asm volatile("s_waitcnt vmcnt(4)" ::: "memory");
        } else {
            asm volatile("s_waitcnt vmcnt(8)" ::: "memory");
        }
        __builtin_amdgcn_sched_barrier(0);

        #pragma unroll
        for (int i = 0; i < 4; ++i) {
            const f32x4 v = *reinterpret_cast<const f32x4*>(
                &Lw[cur * 1024 + i * 256 + lane * 4]);
            *reinterpret_cast<f32x4*>(
                ow + (size_t)i * T_ + (size_t)(t * TW + lane * 4)) = v;
        }
    }
}

// ---------------------------------------------------------------------------
// Stage 2: combine chunk partials -> corr -> threshold -> adj
// ---------------------------------------------------------------------------
__global__ __launch_bounds__(256) void corr_stage2(
    const float* __restrict__ P, const float* __restrict__ S,
    float* __restrict__ adj, int split)
{
    const int idx = blockIdx.x * 256 + threadIdx.x;   // < 128*4096
    const int b  = idx >> 12;
    const int nm = idx & 4095;
    const int n  = nm >> 6;
    const int m  = nm & 63;

    float G = 0.f, Gnn = 0.f, Gmm = 0.f, Sn = 0.f, Sm = 0.f;
    for (int c = 0; c < split; ++c) {
        const float* Pc = P + ((size_t)(b * split + c) << 12);
        const float* Sc = S + (size_t)(b * split + c) * NCH;
        G   += Pc[nm];
        Gnn += Pc[n * 65];
        Gmm += Pc[m * 65];
        Sn  += Sc[n];
        Sm  += Sc[m];
    }
    const float invT = 1.0f / (float)T_;
    const float cov  = G   - Sn * Sm * invT;
    const float vn   = Gnn - Sn * Sn * invT;
    const float vm   = Gmm - Sm * Sm * invT;
    const float den  = sqrtf(vn) * sqrtf(vm) + EPSF;
    float corr = cov / den;
    if (n == m) corr = 0.f;
    adj[idx] = (fabsf(corr) >= THRF) ? corr : 0.f;
}

// ---------------------------------------------------------------------------
extern "C" void kernel_launch(void* const* d_in, const int* in_sizes, int n_in,
                              void* d_out, int out_size, void* d_ws, size_t ws_size,
                              hipStream_t stream)
{
    const float* x   = (const float*)d_in[0];
    float* out   = (float*)d_out;
    float* adj   = out;                                  // 128*64*64
    float* out_x = out + (size_t)B_ * NCH * NCH;         // passthrough x

    const int split = 2;                                 // 256 blocks, 1/CU
    float* P = (float*)d_ws;
    float* S = P + (size_t)B_ * split * 4096;
    const int Tc = T_ / split;                           // 15360, NT=60

    corr_gram<<<dim3(B_ * split), dim3(1024), 131072, stream>>>(x, P, S, split, Tc);
    corr_copy<<<dim3(B_ * split), dim3(1024), 131072, stream>>>(x, out_x, split, Tc);
    corr_stage2<<<dim3((B_ * 4096) / 256), dim3(256), 0, stream>>>(P, S, adj, split);
}

// Round 15
// 450.663 us; speedup vs baseline: 1.3146x; 1.3146x over previous
//
#include <hip/hip_runtime.h>
#include <hip/hip_bf16.h>
#include <cstdint>
#include <cstddef>

#define B_   128
#define NCH  64
#define T_   30720
#define TW   256          // tile t-width: 1 KB contiguous per channel
#define EPSF 1e-12f
#define THRF 0.5f

typedef float  f32x4 __attribute__((ext_vector_type(4)));
typedef short  s16x8 __attribute__((ext_vector_type(8)));
typedef unsigned short u16;

static __device__ __forceinline__ short bf16s(float f) {
    return (short)__builtin_bit_cast(u16, __float2bfloat16(f));
}

// ---------------------------------------------------------------------------
// Stage 1: producer/consumer with PLAIN-REGISTER staging (m13 copy pattern).
// R14 ablation: aggregate BW is ~5.1 TB/s regardless of kernel composition
// on the DMA machinery; m13's plain f32x4 copy does 6.29. This round swaps
// the staging machinery: copy waves global_load f32x4 (1 KB contiguous per
// instr) into dual register banks, then {plain store to out_x + ds_write
// to LDS + fp32 csum}. Gram waves (R13 verbatim) consume LDS one tile
// behind. 1024 thr / 16 waves, split=2 -> 256 blocks = 1/CU, 128 KB LDS.
// Pipeline (61 barrier slots, NT=60):
//   slot t: copy: issue LD(bank, t+1); s_waitcnt vmcnt(16) [LD(t) retired,
//           ST(t-1)+LD(t+1) in flight]; consume bank: 8x {store 1KB row,
//           ds_write swizzled, csum}; lgkmcnt(0); s_barrier.
//           gram: tile t-1 from buf[(t-1)&1]: 32 ds_read_b128, cvt->bf16,
//           16 MFMA (quadrant x K-parity split); s_barrier.
// LDS layout: logical granule g of row r at physical g^(r&7) (16B granules)
// -> ds_write slot = lane^i (row = w*8+i), gram reads ^fs -- R13-identical.
// bf16 Gram (symmetric, transpose-immune); corr err ~4e-3 << 0.108 thresh.
// ---------------------------------------------------------------------------
__global__ __launch_bounds__(1024) void corr_stage1(
    const float* __restrict__ x, float* __restrict__ out_x,
    float* __restrict__ P, float* __restrict__ S,
    int split, int Tc)
{
    extern __shared__ __align__(16) float lds[];   // [2][64][TW] = 128 KB

    const int tid  = threadIdx.x;
    const int lane = tid & 63;
    const int w    = tid >> 6;          // wave 0..15

    const int bid = blockIdx.x;
    const int b   = bid / split;
    const int c   = bid - b * split;

    const size_t base = (size_t)b * ((size_t)NCH * T_) + (size_t)c * Tc;
    const float* xw = x + base;
    float*       ow = out_x + base;

    const int NT  = Tc / TW;            // 60
    const int BUF = NCH * TW;           // 16384 floats

    if (w < 8) {
        // ============ COPY waves: rows w*8 .. w*8+7 ============
        const float* xr = xw + (size_t)(w * 8) * T_ + (size_t)(lane * 4);
        float*       or_ = ow + (size_t)(w * 8) * T_ + (size_t)(lane * 4);

        float csum[8];
        #pragma unroll
        for (int i = 0; i < 8; ++i) csum[i] = 0.f;

        f32x4 A[8], Bk[8];

        auto LD = [&](f32x4* bank, int tt) {
            #pragma unroll
            for (int i = 0; i < 8; ++i)
                bank[i] = *reinterpret_cast<const f32x4*>(
                    xr + (size_t)i * T_ + (size_t)(tt * TW));
        };
        auto CONS = [&](f32x4* bank, int tt) {
            #pragma unroll
            for (int i = 0; i < 8; ++i) {
                const f32x4 v = bank[i];
                *reinterpret_cast<f32x4*>(or_ + (size_t)i * T_ + (size_t)(tt * TW)) = v;
                // row = w*8+i -> row&7 == i; physical slot = lane^i
                lds[(tt & 1) * BUF + (w * 8 + i) * TW + ((lane ^ i) << 2)] = v.x;
                *reinterpret_cast<f32x4*>(
                    &lds[(tt & 1) * BUF + (w * 8 + i) * TW + ((lane ^ i) << 2)]) = v;
                csum[i] += ((v.x + v.y) + (v.z + v.w));
            }
        };
        #define CBAR() do { \
            asm volatile("s_waitcnt lgkmcnt(0)" ::: "memory"); \
            __builtin_amdgcn_s_barrier(); \
            __builtin_amdgcn_sched_barrier(0); } while (0)

        LD(A, 0);
        // slot 0
        LD(Bk, 1);
        asm volatile("s_waitcnt vmcnt(8)" ::: "memory");
        CONS(A, 0);  CBAR();
        // slots 1..58
        for (int t = 1; t <= 57; t += 2) {
            LD(A, t + 1);
            asm volatile("s_waitcnt vmcnt(16)" ::: "memory");
            CONS(Bk, t);  CBAR();
            LD(Bk, t + 2);
            asm volatile("s_waitcnt vmcnt(16)" ::: "memory");
            CONS(A, t + 1);  CBAR();
        }
        // slot 59 (no further LD)
        asm volatile("s_waitcnt vmcnt(8)" ::: "memory");
        CONS(Bk, 59);  CBAR();
        // slot 60 (idle)
        CBAR();
        #undef CBAR

        __syncthreads();

        #pragma unroll
        for (int i = 0; i < 8; ++i) {
            float v = csum[i];
            v += __shfl_xor(v, 1,  64);
            v += __shfl_xor(v, 2,  64);
            v += __shfl_xor(v, 4,  64);
            v += __shfl_xor(v, 8,  64);
            v += __shfl_xor(v, 16, 64);
            v += __shfl_xor(v, 32, 64);
            if (lane == 0)
                S[(size_t)bid * NCH + w * 8 + i] = v;
        }
    } else {
        // ============ GRAM waves (R13 verbatim, one tile behind) ============
        const int g   = w - 8;
        const int q   = g & 3;
        const int par = g >> 2;
        const int qr  = q >> 1, qc = q & 1;
        const int fr  = lane & 15;
        const int g8  = lane >> 4;
        const int fs  = fr & 7;

        f32x4 acc[2][2];
        #pragma unroll
        for (int rb = 0; rb < 2; ++rb)
            #pragma unroll
            for (int cb = 0; cb < 2; ++cb) acc[rb][cb] = (f32x4)(0.f);

        #define GBAR() do { \
            __builtin_amdgcn_s_barrier(); \
            __builtin_amdgcn_sched_barrier(0); } while (0)

        GBAR();   // slot 0: copy produces tile 0
        for (int t = 0; t < NT; ++t) {   // slots 1..60
            const int cur = t & 1;
            #pragma unroll
            for (int kk = 0; kk < 4; ++kk) {
                const int ks = par + 2 * kk;
                const int gl = (ks * 8 + 2 * g8) ^ fs;
                const int gh = (ks * 8 + 2 * g8 + 1) ^ fs;
                s16x8 frag[4];
                #pragma unroll
                for (int e = 0; e < 4; ++e) {
                    const int blk = (e < 2) ? (2 * qr + e) : (2 * qc + (e - 2));
                    const int ro  = cur * BUF + (blk * 16 + fr) * TW;
                    const f32x4 lo = *reinterpret_cast<const f32x4*>(&lds[ro + gl * 4]);
                    const f32x4 hv = *reinterpret_cast<const f32x4*>(&lds[ro + gh * 4]);
                    frag[e][0] = bf16s(lo.x); frag[e][1] = bf16s(lo.y);
                    frag[e][2] = bf16s(lo.z); frag[e][3] = bf16s(lo.w);
                    frag[e][4] = bf16s(hv.x); frag[e][5] = bf16s(hv.y);
                    frag[e][6] = bf16s(hv.z); frag[e][7] = bf16s(hv.w);
                }
                #pragma unroll
                for (int rb = 0; rb < 2; ++rb)
                    #pragma unroll
                    for (int cb = 0; cb < 2; ++cb)
                        acc[rb][cb] = __builtin_amdgcn_mfma_f32_16x16x32_bf16(
                            frag[rb], frag[2 + cb], acc[rb][cb], 0, 0, 0);
            }
            GBAR();
        }
        #undef GBAR

        // odd-parity waves stash acc into buf0 rows 0..15 (no longer read)
        if (par == 1) {
            #pragma unroll
            for (int rb = 0; rb < 2; ++rb)
                #pragma unroll
                for (int cb = 0; cb < 2; ++cb)
                    #pragma unroll
                    for (int reg = 0; reg < 4; ++reg)
                        lds[q * 1024 + lane * 16 + rb * 8 + cb * 4 + reg]
                            = acc[rb][cb][reg];
        }

        __syncthreads();

        if (par == 0) {
            float* Pc = P + ((size_t)bid << 12);
            const int prow = (lane >> 4) << 2;
            const int pcol = lane & 15;
            #pragma unroll
            for (int rb = 0; rb < 2; ++rb)
                #pragma unroll
                for (int cb = 0; cb < 2; ++cb)
                    #pragma unroll
                    for (int reg = 0; reg < 4; ++reg)
                        Pc[((2 * qr + rb) * 16 + prow + reg) * 64
                           + (2 * qc + cb) * 16 + pcol]
                            = acc[rb][cb][reg]
                            + lds[q * 1024 + lane * 16 + rb * 8 + cb * 4 + reg];
        }
    }
}

// ---------------------------------------------------------------------------
// Stage 2: combine chunk partials -> corr -> threshold -> adj
// ---------------------------------------------------------------------------
__global__ __launch_bounds__(256) void corr_stage2(
    const float* __restrict__ P, const float* __restrict__ S,
    float* __restrict__ adj, int split)
{
    const int idx = blockIdx.x * 256 + threadIdx.x;   // < 128*4096
    const int b  = idx >> 12;
    const int nm = idx & 4095;
    const int n  = nm >> 6;
    const int m  = nm & 63;

    float G = 0.f, Gnn = 0.f, Gmm = 0.f, Sn = 0.f, Sm = 0.f;
    for (int c = 0; c < split; ++c) {
        const float* Pc = P + ((size_t)(b * split + c) << 12);
        const float* Sc = S + (size_t)(b * split + c) * NCH;
        G   += Pc[nm];
        Gnn += Pc[n * 65];
        Gmm += Pc[m * 65];
        Sn  += Sc[n];
        Sm  += Sc[m];
    }
    const float invT = 1.0f / (float)T_;
    const float cov  = G   - Sn * Sm * invT;
    const float vn   = Gnn - Sn * Sn * invT;
    const float vm   = Gmm - Sm * Sm * invT;
    const float den  = sqrtf(vn) * sqrtf(vm) + EPSF;
    float corr = cov / den;
    if (n == m) corr = 0.f;
    adj[idx] = (fabsf(corr) >= THRF) ? corr : 0.f;
}

// ---------------------------------------------------------------------------
extern "C" void kernel_launch(void* const* d_in, const int* in_sizes, int n_in,
                              void* d_out, int out_size, void* d_ws, size_t ws_size,
                              hipStream_t stream)
{
    const float* x   = (const float*)d_in[0];
    float* out   = (float*)d_out;
    float* adj   = out;                                  // 128*64*64
    float* out_x = out + (size_t)B_ * NCH * NCH;         // passthrough x

    const int split = 2;                                 // 256 blocks, 1/CU
    float* P = (float*)d_ws;
    float* S = P + (size_t)B_ * split * 4096;
    const int Tc = T_ / split;                           // 15360, NT=60

    corr_stage1<<<dim3(B_ * split), dim3(1024), 131072, stream>>>(
        x, out_x, P, S, split, Tc);
    corr_stage2<<<dim3((B_ * 4096) / 256), dim3(256), 0, stream>>>(P, S, adj, split);
}

// Round 16
// 438.402 us; speedup vs baseline: 1.3514x; 1.0280x over previous
//
#include <hip/hip_runtime.h>
#include <hip/hip_bf16.h>
#include <cstdint>
#include <cstddef>

#define B_   128
#define NCH  64
#define T_   30720
#define TW   256          // tile t-width: 1 KB contiguous per channel per tile
#define EPSF 1e-12f
#define THRF 0.5f

typedef float  f32x4 __attribute__((ext_vector_type(4)));
typedef short  s16x8 __attribute__((ext_vector_type(8)));
typedef unsigned short u16;

#define AS1 __attribute__((address_space(1)))
#define AS3 __attribute__((address_space(3)))

static __device__ __forceinline__ short bf16s(float f) {
    return (short)__builtin_bit_cast(u16, __float2bfloat16(f));
}

// ---------------------------------------------------------------------------
// FINAL (R13 revert — measured best, 428.5 us):
// DMA-staged streaming Gram + fused copy, 1 KB-chunk, producer/consumer.
// tile [64ch][256t] f32 (64 KB), double-buffered = 128 KB dynamic LDS,
// 1024 thr / 16 waves, split=2 -> 256 blocks = 1 block/CU.
//   all 16 waves: 4 DMA instrs each (global_load_lds dwordx4), one FULL
//                 1 KB channel-row per instr.
//   waves 0-7  COPY: 8 rows each: ds_read row -> linear 1 KB cached store +
//              fp32 row sums; vmcnt(8) (stores fly across barrier).
//   waves 8-15 GRAM: quadrant q=(w-8)&3, K-parity par=(w-8)>>2; per owned
//              K-step (4 of 8): 8 ds_read_b128, cvt->bf16, 4 MFMA; vmcnt(0).
//   one s_barrier per tile; buffer flip.
// Epilogue: odd-parity waves stash acc in buf0; __syncthreads; even-parity
// waves write (own acc + stash) to their exclusive P quadrant; copy waves
// write S. LDS swizzle: granule^(row&7) via pre-swizzled DMA source.
// bf16 Gram (symmetric, transpose-immune); corr err ~4e-3 << 0.108 thresh.
//
// Roofline note: R14 ablation shows this op's access pattern (64 streams/
// block at 120 KB stride, 1 KB chunks — forced by Gram needing all channels'
// matching t-windows) caps DRAM at ~5.1-5.4 TB/s vs 6.3 linear; traffic is
// minimal (2.01 GB). 428 us ~= pattern floor + pipeline fill/epilogue.
// ---------------------------------------------------------------------------
__global__ __launch_bounds__(1024) void corr_stage1(
    const float* __restrict__ x, float* __restrict__ out_x,
    float* __restrict__ P, float* __restrict__ S,
    int split, int Tc)
{
    extern __shared__ __align__(16) float lds[];   // [2][64][TW] = 128 KB

    const int tid  = threadIdx.x;
    const int lane = tid & 63;
    const int w    = tid >> 6;          // wave 0..15

    const int bid = blockIdx.x;
    const int b   = bid / split;
    const int c   = bid - b * split;

    const size_t base = (size_t)b * ((size_t)NCH * T_) + (size_t)c * Tc;
    const float* xw = x + base;
    float*       ow = out_x + base;

    const int NT  = Tc / TW;            // 60
    const int BUF = NCH * TW;           // 16384

    auto dma = [&](int tile, int buf) {
        #pragma unroll
        for (int i = 0; i < 4; ++i) {
            const int r  = w * 4 + i;
            const int gg = lane ^ (r & 7);            // pre-swizzled source
            const float* src = xw + (size_t)r * T_ + (size_t)(tile * TW + gg * 4);
            float* dst = &lds[buf * BUF + r * TW];    // wave-uniform, linear
            __builtin_amdgcn_global_load_lds((const AS1 void*)src,
                                             (AS3 void*)dst, 16, 0, 0);
        }
    };

    dma(0, 0);
    asm volatile("s_waitcnt vmcnt(0)" ::: "memory");
    __builtin_amdgcn_s_barrier();
    __builtin_amdgcn_sched_barrier(0);

    if (w < 8) {
        // ============ COPY + S waves (rows w*8 .. w*8+7) ============
        float csum[8];
        #pragma unroll
        for (int i = 0; i < 8; ++i) csum[i] = 0.f;

        for (int t = 0; t < NT; ++t) {
            const int cur = t & 1;
            if (t + 1 < NT) dma(t + 1, cur ^ 1);

            #pragma unroll
            for (int i = 0; i < 8; ++i) {
                const int row  = w * 8 + i;
                const int slot = lane ^ (row & 7);    // undo source swizzle
                const f32x4 v = *reinterpret_cast<const f32x4*>(
                    &lds[cur * BUF + row * TW + slot * 4]);
                *reinterpret_cast<f32x4*>(
                    ow + (size_t)row * T_ + (size_t)(t * TW + lane * 4)) = v;
                csum[i] += ((v.x + v.y) + (v.z + v.w));
            }

            asm volatile("s_waitcnt vmcnt(8)" ::: "memory");
            __builtin_amdgcn_s_barrier();
            __builtin_amdgcn_sched_barrier(0);
        }

        __syncthreads();   // match Gram waves' epilogue barrier

        #pragma unroll
        for (int i = 0; i < 8; ++i) {
            float v = csum[i];
            v += __shfl_xor(v, 1,  64);
            v += __shfl_xor(v, 2,  64);
            v += __shfl_xor(v, 4,  64);
            v += __shfl_xor(v, 8,  64);
            v += __shfl_xor(v, 16, 64);
            v += __shfl_xor(v, 32, 64);
            if (lane == 0)
                S[(size_t)bid * NCH + w * 8 + i] = v;
        }
    } else {
        // ============ GRAM waves ============
        const int g   = w - 8;
        const int q   = g & 3;
        const int par = g >> 2;
        const int qr  = q >> 1, qc = q & 1;
        const int fr  = lane & 15;
        const int g8  = lane >> 4;
        const int fs  = fr & 7;

        f32x4 acc[2][2];
        #pragma unroll
        for (int rb = 0; rb < 2; ++rb)
            #pragma unroll
            for (int cb = 0; cb < 2; ++cb) acc[rb][cb] = (f32x4)(0.f);

        for (int t = 0; t < NT; ++t) {
            const int cur = t & 1;
            if (t + 1 < NT) dma(t + 1, cur ^ 1);

            #pragma unroll
            for (int kk = 0; kk < 4; ++kk) {
                const int ks = par + 2 * kk;
                const int gl = (ks * 8 + 2 * g8) ^ fs;
                const int gh = (ks * 8 + 2 * g8 + 1) ^ fs;
                s16x8 frag[4];
                #pragma unroll
                for (int e = 0; e < 4; ++e) {
                    const int blk = (e < 2) ? (2 * qr + e) : (2 * qc + (e - 2));
                    const int ro  = cur * BUF + (blk * 16 + fr) * TW;
                    const f32x4 lo = *reinterpret_cast<const f32x4*>(&lds[ro + gl * 4]);
                    const f32x4 hv = *reinterpret_cast<const f32x4*>(&lds[ro + gh * 4]);
                    frag[e][0] = bf16s(lo.x); frag[e][1] = bf16s(lo.y);
                    frag[e][2] = bf16s(lo.z); frag[e][3] = bf16s(lo.w);
                    frag[e][4] = bf16s(hv.x); frag[e][5] = bf16s(hv.y);
                    frag[e][6] = bf16s(hv.z); frag[e][7] = bf16s(hv.w);
                }
                #pragma unroll
                for (int rb = 0; rb < 2; ++rb)
                    #pragma unroll
                    for (int cb = 0; cb < 2; ++cb)
                        acc[rb][cb] = __builtin_amdgcn_mfma_f32_16x16x32_bf16(
                            frag[rb], frag[2 + cb], acc[rb][cb], 0, 0, 0);
            }

            asm volatile("s_waitcnt vmcnt(0)" ::: "memory");
            __builtin_amdgcn_s_barrier();
            __builtin_amdgcn_sched_barrier(0);
        }

        // odd-parity waves stash acc into buf0 rows 0..15 (no longer read)
        if (par == 1) {
            #pragma unroll
            for (int rb = 0; rb < 2; ++rb)
                #pragma unroll
                for (int cb = 0; cb < 2; ++cb)
                    #pragma unroll
                    for (int reg = 0; reg < 4; ++reg)
                        lds[q * 1024 + lane * 16 + rb * 8 + cb * 4 + reg]
                            = acc[rb][cb][reg];
        }

        __syncthreads();

        if (par == 0) {
            float* Pc = P + ((size_t)bid << 12);
            const int prow = (lane >> 4) << 2;
            const int pcol = lane & 15;
            #pragma unroll
            for (int rb = 0; rb < 2; ++rb)
                #pragma unroll
                for (int cb = 0; cb < 2; ++cb)
                    #pragma unroll
                    for (int reg = 0; reg < 4; ++reg)
                        Pc[((2 * qr + rb) * 16 + prow + reg) * 64
                           + (2 * qc + cb) * 16 + pcol]
                            = acc[rb][cb][reg]
                            + lds[q * 1024 + lane * 16 + rb * 8 + cb * 4 + reg];
        }
    }
}

// ---------------------------------------------------------------------------
// Stage 2: combine chunk partials -> corr -> threshold -> adj
// ---------------------------------------------------------------------------
__global__ __launch_bounds__(256) void corr_stage2(
    const float* __restrict__ P, const float* __restrict__ S,
    float* __restrict__ adj, int split)
{
    const int idx = blockIdx.x * 256 + threadIdx.x;   // < 128*4096
    const int b  = idx >> 12;
    const int nm = idx & 4095;
    const int n  = nm >> 6;
    const int m  = nm & 63;

    float G = 0.f, Gnn = 0.f, Gmm = 0.f, Sn = 0.f, Sm = 0.f;
    for (int c = 0; c < split; ++c) {
        const float* Pc = P + ((size_t)(b * split + c) << 12);
        const float* Sc = S + (size_t)(b * split + c) * NCH;
        G   += Pc[nm];
        Gnn += Pc[n * 65];
        Gmm += Pc[m * 65];
        Sn  += Sc[n];
        Sm  += Sc[m];
    }
    const float invT = 1.0f / (float)T_;
    const float cov  = G   - Sn * Sm * invT;
    const float vn   = Gnn - Sn * Sn * invT;
    const float vm   = Gmm - Sm * Sm * invT;
    const float den  = sqrtf(vn) * sqrtf(vm) + EPSF;
    float corr = cov / den;
    if (n == m) corr = 0.f;
    adj[idx] = (fabsf(corr) >= THRF) ? corr : 0.f;
}

// ---------------------------------------------------------------------------
extern "C" void kernel_launch(void* const* d_in, const int* in_sizes, int n_in,
                              void* d_out, int out_size, void* d_ws, size_t ws_size,
                              hipStream_t stream)
{
    const float* x   = (const float*)d_in[0];
    float* out   = (float*)d_out;
    float* adj   = out;                                  // 128*64*64
    float* out_x = out + (size_t)B_ * NCH * NCH;         // passthrough x

    // split=2 -> 256 blocks of 1024 thr = 1 block/CU (128 KB dynamic LDS).
    const int split = 2;
    float* P = (float*)d_ws;
    float* S = P + (size_t)B_ * split * 4096;
    const int Tc = T_ / split;                           // 15360, NT=60

    corr_stage1<<<dim3(B_ * split), dim3(1024), 131072, stream>>>(
        x, out_x, P, S, split, Tc);
    corr_stage2<<<dim3((B_ * 4096) / 256), dim3(256), 0, stream>>>(P, S, adj, split);
}